// Round 8
// baseline (87.869 us; speedup 1.0000x reference)
//
#include <hip/hip_runtime.h>

// Head: fused QKV projection + causal attention, MI355X (gfx950)
// B=512, T=256, C=384, D=64. fp32 in/out, bf16 MFMA compute.
// 512 blocks x 512 thr = 2 blocks/CU co-resident (LDS 77.8KB, VGPR<=128).
// Phase 1: flat tiling (wave w: 16 rows x 192 cols), x global->reg,
// W single-buffered in LDS. Q stays in REGISTERS via pi-permuted k-mapping;
// K stored pi-permuted in LDS so QK^T needs no Q LDS at all.
// Phase 2: kv-chunk=32, wave w handles q-tiles {w, 15-w} (9 chunks each).

typedef short s16x8 __attribute__((ext_vector_type(8)));
typedef float f32x4 __attribute__((ext_vector_type(4)));
typedef float f32x2 __attribute__((ext_vector_type(2)));
typedef unsigned int u32;
typedef unsigned int u32x4 __attribute__((ext_vector_type(4)));
typedef unsigned short u16;
typedef unsigned short u16x4 __attribute__((ext_vector_type(4)));
typedef __bf16 bf16x2 __attribute__((ext_vector_type(2)));

__device__ __forceinline__ u32 cvt2(float x, float y) {
  f32x2 v = {x, y};
  bf16x2 b = __builtin_convertvector(v, bf16x2);
  return __builtin_bit_cast(u32, b);
}
__device__ __forceinline__ u16 f2bf(float f) {
  __bf16 b = (__bf16)f;
  return __builtin_bit_cast(u16, b);
}
__device__ __forceinline__ s16x8 pack8(float4 a, float4 b) {
  u32x4 p = {cvt2(a.x, a.y), cvt2(a.z, a.w), cvt2(b.x, b.y), cvt2(b.z, b.w)};
  return __builtin_bit_cast(s16x8, p);
}
__device__ __forceinline__ s16x8 mk_qf(f32x4 a, f32x4 b) {
  u32x4 p = {cvt2(a[0], a[1]), cvt2(a[2], a[3]), cvt2(b[0], b[1]), cvt2(b[2], b[3])};
  return __builtin_bit_cast(s16x8, p);
}

#define MFMA16 __builtin_amdgcn_mfma_f32_16x16x32_bf16

// LDS: [0,32768) K (pi-permuted, row-swizzled) | [32768,65536) V^T |
//      [65536,77824) W stage (phase1) / P buffers (phase2)
#define VTOF 32768
#define WOFF 65536

__device__ __forceinline__ void w_write(char* smem, int wrow, int wslot,
                                        float4 a, float4 b) {
  *reinterpret_cast<s16x8*>(smem + WOFF + wrow * 64 + ((wslot ^ (wrow & 3)) << 4)) =
      pack8(a, b);
}

__device__ __forceinline__ void p1_compute(const char* smem, f32x4 (&acc)[12],
                                           float4 x0, float4 x1, int g, int li) {
  s16x8 xf = pack8(x0, x1);
#pragma unroll
  for (int h = 0; h < 3; ++h) {
    s16x8 a0 = *reinterpret_cast<const s16x8*>(
        smem + WOFF + ((h * 4 + 0) * 16 + li) * 64 + ((g ^ (li & 3)) << 4));
    s16x8 a1 = *reinterpret_cast<const s16x8*>(
        smem + WOFF + ((h * 4 + 1) * 16 + li) * 64 + ((g ^ (li & 3)) << 4));
    s16x8 a2 = *reinterpret_cast<const s16x8*>(
        smem + WOFF + ((h * 4 + 2) * 16 + li) * 64 + ((g ^ (li & 3)) << 4));
    s16x8 a3 = *reinterpret_cast<const s16x8*>(
        smem + WOFF + ((h * 4 + 3) * 16 + li) * 64 + ((g ^ (li & 3)) << 4));
    acc[h * 4 + 0] = MFMA16(a0, xf, acc[h * 4 + 0], 0, 0, 0);
    acc[h * 4 + 1] = MFMA16(a1, xf, acc[h * 4 + 1], 0, 0, 0);
    acc[h * 4 + 2] = MFMA16(a2, xf, acc[h * 4 + 2], 0, 0, 0);
    acc[h * 4 + 3] = MFMA16(a3, xf, acc[h * 4 + 3], 0, 0, 0);
  }
}

// One projection pass: 128 x-rows (this wave: rows kvrow..), 12 k-tiles,
// single-buffered W (2 barriers/tile), W loads issued one tile early.
// Epilogue: Q -> qf regs (pi-native), K -> LDS (pi-permuted), V -> Vt LDS.
__device__ __forceinline__ void p1_pass(
    const float* __restrict__ xg, const float* __restrict__ wsrc1,
    const float* __restrict__ wsrc2, char* __restrict__ smem,
    f32x4 (&acc)[12], s16x8& qf0, s16x8& qf1,
    const int tid, const int g, const int li, const int kvrow)
{
  const int wrow1 = tid >> 2, wslot = tid & 3, wrow2 = wrow1 + 128;
  const bool dow2 = (tid < 256);

  float4 ax0 = *reinterpret_cast<const float4*>(xg);
  float4 ax1 = *reinterpret_cast<const float4*>(xg + 4);
  float4 bx0, bx1;
  float4 wa0, wa1, wb0, wb1;
  wa0 = *reinterpret_cast<const float4*>(wsrc1);
  wa1 = *reinterpret_cast<const float4*>(wsrc1 + 4);
  if (dow2) {
    wb0 = *reinterpret_cast<const float4*>(wsrc2);
    wb1 = *reinterpret_cast<const float4*>(wsrc2 + 4);
  }
  w_write(smem, wrow1, wslot, wa0, wa1);
  if (dow2) w_write(smem, wrow2, wslot, wb0, wb1);
  __syncthreads();

#pragma unroll 1
  for (int it = 0; it < 6; ++it) {
    const int t = it * 2;
    if (t < 11) {                         // prefetch tile t+1 (regs)
      bx0 = *reinterpret_cast<const float4*>(xg + (t + 1) * 32);
      bx1 = *reinterpret_cast<const float4*>(xg + (t + 1) * 32 + 4);
      wa0 = *reinterpret_cast<const float4*>(wsrc1 + (t + 1) * 32);
      wa1 = *reinterpret_cast<const float4*>(wsrc1 + (t + 1) * 32 + 4);
      if (dow2) {
        wb0 = *reinterpret_cast<const float4*>(wsrc2 + (t + 1) * 32);
        wb1 = *reinterpret_cast<const float4*>(wsrc2 + (t + 1) * 32 + 4);
      }
    }
    p1_compute(smem, acc, ax0, ax1, g, li);
    __syncthreads();
    if (t < 11) {
      w_write(smem, wrow1, wslot, wa0, wa1);
      if (dow2) w_write(smem, wrow2, wslot, wb0, wb1);
    }
    __syncthreads();

    if (t + 2 < 12) {                     // prefetch tile t+2
      ax0 = *reinterpret_cast<const float4*>(xg + (t + 2) * 32);
      ax1 = *reinterpret_cast<const float4*>(xg + (t + 2) * 32 + 4);
      wa0 = *reinterpret_cast<const float4*>(wsrc1 + (t + 2) * 32);
      wa1 = *reinterpret_cast<const float4*>(wsrc1 + (t + 2) * 32 + 4);
      if (dow2) {
        wb0 = *reinterpret_cast<const float4*>(wsrc2 + (t + 2) * 32);
        wb1 = *reinterpret_cast<const float4*>(wsrc2 + (t + 2) * 32 + 4);
      }
    }
    p1_compute(smem, acc, bx0, bx1, g, li);
    __syncthreads();
    if (t + 2 < 12) {
      w_write(smem, wrow1, wslot, wa0, wa1);
      if (dow2) w_write(smem, wrow2, wslot, wb0, wb1);
    }
    __syncthreads();
  }

  // ---- epilogue: lane (g,li) holds D[n=16nt+4g+r][row=kvrow] ----
  qf0 = mk_qf(acc[0], acc[1]);            // Q dims {32*0+4g+r, +16}: pi-native
  qf1 = mk_qf(acc[2], acc[3]);
#pragma unroll
  for (int mm = 0; mm < 4; ++mm) {        // K: dim D=16mm+4g+r -> phys E
    const int Eb = 32 * (mm >> 1) + 8 * g + 4 * (mm & 1);
    u16x4 pk;
    pk[0] = f2bf(acc[4 + mm][0]); pk[1] = f2bf(acc[4 + mm][1]);
    pk[2] = f2bf(acc[4 + mm][2]); pk[3] = f2bf(acc[4 + mm][3]);
    *reinterpret_cast<u16x4*>(smem + kvrow * 128 +
        (((Eb >> 3) ^ (kvrow & 7)) << 4) + (Eb & 7) * 2) = pk;
  }
#pragma unroll
  for (int mm = 0; mm < 4; ++mm)          // V transposed
#pragma unroll
    for (int r = 0; r < 4; ++r) {
      const int d = mm * 16 + 4 * g + r;
      *reinterpret_cast<u16*>(smem + VTOF + d * 512 +
          ((kvrow * 2) ^ ((d & 7) << 4))) = f2bf(acc[8 + mm][r]);
    }
#pragma unroll
  for (int nt = 0; nt < 12; ++nt) acc[nt] = (f32x4){0.f, 0.f, 0.f, 0.f};
}

// Phase 2: one q-tile, kv-chunk=32, online softmax, P stride-80 LDS.
__device__ __forceinline__ void attn_round(
    char* __restrict__ smem, char* __restrict__ Pw,
    float* __restrict__ outb, const int qt,
    const s16x8 qf0, const s16x8 qf1, const int g, const int li)
{
  f32x4 o[4];
  float mx[4], ls[4];
#pragma unroll
  for (int r = 0; r < 4; ++r) { mx[r] = -1e30f; ls[r] = 0.f; }
#pragma unroll
  for (int nd = 0; nd < 4; ++nd) o[nd] = (f32x4){0.f, 0.f, 0.f, 0.f};

  const int nc = (qt >> 1) + 1;
#pragma unroll 1
  for (int c = 0; c < nc; ++c) {
    f32x4 s0 = {0.f, 0.f, 0.f, 0.f}, s1 = {0.f, 0.f, 0.f, 0.f};
    const int rb0 = c * 32 + li, rb1 = rb0 + 16;
    s16x8 k00 = *reinterpret_cast<const s16x8*>(
        smem + rb0 * 128 + (((g) ^ (rb0 & 7)) << 4));
    s16x8 k01 = *reinterpret_cast<const s16x8*>(
        smem + rb0 * 128 + (((4 + g) ^ (rb0 & 7)) << 4));
    s16x8 k10 = *reinterpret_cast<const s16x8*>(
        smem + rb1 * 128 + (((g) ^ (rb1 & 7)) << 4));
    s16x8 k11 = *reinterpret_cast<const s16x8*>(
        smem + rb1 * 128 + (((4 + g) ^ (rb1 & 7)) << 4));
    s0 = MFMA16(qf0, k00, s0, 0, 0, 0);
    s0 = MFMA16(qf1, k01, s0, 0, 0, 0);
    s1 = MFMA16(qf0, k10, s1, 0, 0, 0);
    s1 = MFMA16(qf1, k11, s1, 0, 0, 0);

    const bool last = (c == nc - 1);
    float alpha[4];
#pragma unroll
    for (int r = 0; r < 4; ++r) {
      float v0 = s0[r] * 0.125f, v1 = s1[r] * 0.125f;
      if (last) {
        const int qrow = qt * 16 + 4 * g + r;
        if (c * 32 + li > qrow) v0 = -1e30f;
        if (c * 32 + 16 + li > qrow) v1 = -1e30f;
      }
      s0[r] = v0; s1[r] = v1;
      float pm = fmaxf(v0, v1);
      pm = fmaxf(pm, __shfl_xor(pm, 1));
      pm = fmaxf(pm, __shfl_xor(pm, 2));
      pm = fmaxf(pm, __shfl_xor(pm, 4));
      pm = fmaxf(pm, __shfl_xor(pm, 8));
      const float mn = fmaxf(mx[r], pm);
      alpha[r] = __expf(mx[r] - mn);
      mx[r] = mn;
    }
    float ps[4];
#pragma unroll
    for (int r = 0; r < 4; ++r) {
      const float p0 = __expf(s0[r] - mx[r]);
      const float p1 = __expf(s1[r] - mx[r]);
      ps[r] = p0 + p1;
      const int rp = 4 * g + r;
      *reinterpret_cast<u16*>(Pw + rp * 80 + li * 2) = f2bf(p0);
      *reinterpret_cast<u16*>(Pw + rp * 80 + 32 + li * 2) = f2bf(p1);
    }
#pragma unroll
    for (int r = 0; r < 4; ++r) {
      float t = ps[r];
      t += __shfl_xor(t, 1);
      t += __shfl_xor(t, 2);
      t += __shfl_xor(t, 4);
      t += __shfl_xor(t, 8);
      ls[r] = ls[r] * alpha[r] + t;
    }
#pragma unroll
    for (int nd = 0; nd < 4; ++nd)
#pragma unroll
      for (int r = 0; r < 4; ++r) o[nd][r] *= alpha[r];

    __asm__ volatile("s_waitcnt lgkmcnt(0)" ::: "memory");
    s16x8 pa = *reinterpret_cast<const s16x8*>(Pw + li * 80 + g * 16);
#pragma unroll
    for (int nd = 0; nd < 4; ++nd) {
      const int d = nd * 16 + li;
      s16x8 vf = *reinterpret_cast<const s16x8*>(
          smem + VTOF + d * 512 + ((c * 64 + g * 16) ^ ((d & 7) << 4)));
      o[nd] = MFMA16(pa, vf, o[nd], 0, 0, 0);
    }
  }
#pragma unroll
  for (int r = 0; r < 4; ++r) ls[r] = 1.f / ls[r];
#pragma unroll
  for (int nd = 0; nd < 4; ++nd)
#pragma unroll
    for (int r = 0; r < 4; ++r)
      outb[(qt * 16 + 4 * g + r) * 64 + nd * 16 + li] = o[nd][r] * ls[r];
}

__global__ __launch_bounds__(512, 4) void head_kernel(
    const float* __restrict__ x,
    const float* __restrict__ WQ, const float* __restrict__ WK,
    const float* __restrict__ WV, float* __restrict__ out)
{
  __shared__ char smem[77824];
  const int tid = threadIdx.x;
  const int l = tid & 63, w = tid >> 6;
  const int g = l >> 4, li = l & 15;
  const long bbase = (long)blockIdx.x * 256;

  const int wrow1 = tid >> 2, wslot = tid & 3;
  const float* wsrc1 = ((wrow1 < 64) ? (WQ + wrow1 * 384)
                                     : (WK + (wrow1 - 64) * 384)) + wslot * 8;
  const float* wsrc2 = WV + wrow1 * 384 + wslot * 8;  // used only when tid<256

  f32x4 acc[12];
#pragma unroll
  for (int nt = 0; nt < 12; ++nt) acc[nt] = (f32x4){0.f, 0.f, 0.f, 0.f};

  s16x8 qfA0, qfA1, qfB0, qfB1;

  {   // pass A: rows [16w, 16w+16) -> q-tile w
    const int rb = w * 16;
    p1_pass(x + (bbase + rb + li) * 384 + g * 8, wsrc1, wsrc2, smem, acc,
            qfA0, qfA1, tid, g, li, rb + li);
  }
  {   // pass B: rows [16(15-w), +16) -> q-tile 15-w
    const int rb = (15 - w) * 16;
    p1_pass(x + (bbase + rb + li) * 384 + g * 8, wsrc1, wsrc2, smem, acc,
            qfB0, qfB1, tid, g, li, rb + li);
  }
  __syncthreads();   // K/V complete; W region becomes P

  char* Pw = smem + WOFF + w * 1536;
  float* outb = out + bbase * 64;
  attn_round(smem, Pw, outb, w, qfA0, qfA1, g, li);
  attn_round(smem, Pw, outb, 15 - w, qfB0, qfB1, g, li);
}

extern "C" void kernel_launch(void* const* d_in, const int* in_sizes, int n_in,
                              void* d_out, int out_size, void* d_ws, size_t ws_size,
                              hipStream_t stream) {
  const float* x  = (const float*)d_in[0];
  const float* WQ = (const float*)d_in[1];
  const float* WK = (const float*)d_in[2];
  const float* WV = (const float*)d_in[3];
  float* out = (float*)d_out;

  head_kernel<<<dim3(512), dim3(512), 0, stream>>>(x, WQ, WK, WV, out);
}

// Round 9
// 63.736 us; speedup vs baseline: 1.3786x; 1.3786x over previous
//
#include <hip/hip_runtime.h>

// Head: fused QKV projection + causal attention, MI355X (gfx950)
// B=512, T=256, C=384, D=64. fp32 in/out, bf16 MFMA compute.
// One block = one batch. 1024 thr = 16 waves, 144 KB LDS, 1 block/CU.
// Phase 1 is ZERO-BARRIER: full W staged to LDS once; wave w streams its
// own 16 x-rows global->reg (depth-2 pipeline); latency hidden by ILP+TLP
// with no __syncthreads vmcnt-drains in the loop. 3 barriers total.
// Q never touches LDS: accumulator fragments feed phase-2 QK^T directly
// via the pi k-permutation; K is stored pi-permuted in LDS to match.

typedef short s16x8 __attribute__((ext_vector_type(8)));
typedef float f32x4 __attribute__((ext_vector_type(4)));
typedef float f32x2 __attribute__((ext_vector_type(2)));
typedef unsigned int u32;
typedef unsigned int u32x4 __attribute__((ext_vector_type(4)));
typedef unsigned short u16;
typedef unsigned short u16x4 __attribute__((ext_vector_type(4)));
typedef __bf16 bf16x2 __attribute__((ext_vector_type(2)));

__device__ __forceinline__ u32 cvt2(float x, float y) {
  f32x2 v = {x, y};
  bf16x2 b = __builtin_convertvector(v, bf16x2);
  return __builtin_bit_cast(u32, b);
}
__device__ __forceinline__ u16 f2bf(float f) {
  __bf16 b = (__bf16)f;
  return __builtin_bit_cast(u16, b);
}
__device__ __forceinline__ s16x8 pack8(float4 a, float4 b) {
  u32x4 p = {cvt2(a.x, a.y), cvt2(a.z, a.w), cvt2(b.x, b.y), cvt2(b.z, b.w)};
  return __builtin_bit_cast(s16x8, p);
}
__device__ __forceinline__ s16x8 mk_qf(f32x4 a, f32x4 b) {
  u32x4 p = {cvt2(a[0], a[1]), cvt2(a[2], a[3]), cvt2(b[0], b[1]), cvt2(b[2], b[3])};
  return __builtin_bit_cast(s16x8, p);
}

#define MFMA16 __builtin_amdgcn_mfma_f32_16x16x32_bf16

// LDS: phase 1: W[192 rows][768 B], 16B slots XOR-swizzled with row&7.
// phase 2 overlay (W retired): K[256][128B] @0 | Vt[64][512B] @32768 |
//                              P[16 waves][2KB] @65536
#define VTOF 32768
#define POFF 65536

__global__ __launch_bounds__(1024) void head_kernel(
    const float* __restrict__ x,
    const float* __restrict__ WQ, const float* __restrict__ WK,
    const float* __restrict__ WV, float* __restrict__ out)
{
  __shared__ char smem[147456];
  const int tid = threadIdx.x;
  const int l  = tid & 63;
  const int w  = tid >> 6;
  const int g  = l >> 4, li = l & 15;
  const long bbase = (long)blockIdx.x * 256;

  const int myrow = 16 * w + li;                 // this lane's x-row (in batch)
  const float* px = x + (bbase + myrow) * 384 + g * 8;

  // ---- issue first two x k-chunks (in flight across W staging) ----
  float4 a0 = *reinterpret_cast<const float4*>(px);
  float4 a1 = *reinterpret_cast<const float4*>(px + 4);
  float4 b0 = *reinterpret_cast<const float4*>(px + 32);
  float4 b1 = *reinterpret_cast<const float4*>(px + 36);

  // ---- stage full W once: 192 rows x 48 slots of 8 f32 -> bf16 ----
#pragma unroll 3
  for (int i = 0; i < 9; ++i) {
    int id = tid + 1024 * i;                     // 0..9215
    int row = id / 48, slot = id - row * 48;
    const float* wsrc = (row < 64) ? (WQ + row * 384)
                       : (row < 128) ? (WK + (row - 64) * 384)
                                     : (WV + (row - 128) * 384);
    float4 wa = *reinterpret_cast<const float4*>(wsrc + slot * 8);
    float4 wb = *reinterpret_cast<const float4*>(wsrc + slot * 8 + 4);
    *reinterpret_cast<s16x8*>(smem + row * 768 + ((slot ^ (row & 7)) << 4)) =
        pack8(wa, wb);
  }
  __syncthreads();                               // barrier #1 (only one before epilogue)

  f32x4 acc[12];
#pragma unroll
  for (int nt = 0; nt < 12; ++nt) acc[nt] = (f32x4){0.f, 0.f, 0.f, 0.f};

  // ---- phase 1: 12 k-tiles, ZERO barriers, depth-2 register pipeline ----
#pragma unroll 1
  for (int t = 0; t < 12; t += 2) {
    s16x8 xfA = pack8(a0, a1);
    if (t + 2 < 12) {
      a0 = *reinterpret_cast<const float4*>(px + (t + 2) * 32);
      a1 = *reinterpret_cast<const float4*>(px + (t + 2) * 32 + 4);
    }
#pragma unroll
    for (int nt = 0; nt < 12; ++nt) {
      const int rw = nt * 16 + li;
      s16x8 af = *reinterpret_cast<const s16x8*>(
          smem + rw * 768 + (((t * 4 + g) ^ (li & 7)) << 4));
      acc[nt] = MFMA16(af, xfA, acc[nt], 0, 0, 0);
    }
    s16x8 xfB = pack8(b0, b1);
    if (t + 3 < 12) {
      b0 = *reinterpret_cast<const float4*>(px + (t + 3) * 32);
      b1 = *reinterpret_cast<const float4*>(px + (t + 3) * 32 + 4);
    }
#pragma unroll
    for (int nt = 0; nt < 12; ++nt) {
      const int rw = nt * 16 + li;
      s16x8 af = *reinterpret_cast<const s16x8*>(
          smem + rw * 768 + ((((t + 1) * 4 + g) ^ (li & 7)) << 4));
      acc[nt] = MFMA16(af, xfB, acc[nt], 0, 0, 0);
    }
  }
  __syncthreads();                               // barrier #2: all W reads done

  // ---- epilogue: lane (g,li) holds D[n=16nt+4g+r][row=myrow] ----
  // Q (acc[0..3]) -> registers, pi-native: qf0/qf1 cover phys k 8g+j with
  // Q-dim 4g+(j&3)+16(j>>2) (+32 for qf1).
  s16x8 qf0 = mk_qf(acc[0], acc[1]);
  s16x8 qf1 = mk_qf(acc[2], acc[3]);
  // K (acc[4..7]) -> LDS pi-permuted: phys elem p holds K[pi(p)].
#pragma unroll
  for (int mm = 0; mm < 4; ++mm) {
    const int Eb = 32 * (mm >> 1) + 8 * g + 4 * (mm & 1);
    u16x4 pk;
    pk[0] = f2bf(acc[4 + mm][0]); pk[1] = f2bf(acc[4 + mm][1]);
    pk[2] = f2bf(acc[4 + mm][2]); pk[3] = f2bf(acc[4 + mm][3]);
    *reinterpret_cast<u16x4*>(smem + myrow * 128 +
        (((Eb >> 3) ^ (myrow & 7)) << 4) + (Eb & 7) * 2) = pk;
  }
  // V (acc[8..11]) -> transposed Vt[d][kv]
#pragma unroll
  for (int mm = 0; mm < 4; ++mm)
#pragma unroll
    for (int r = 0; r < 4; ++r) {
      const int d = mm * 16 + 4 * g + r;
      *reinterpret_cast<u16*>(smem + VTOF + d * 512 +
          ((myrow * 2) ^ ((d & 7) << 4))) = f2bf(acc[8 + mm][r]);
    }
  __syncthreads();                               // barrier #3: K/V ready

  // ---- phase 2: causal attention; wave w owns q-tile qt = w ----
  char* Pw = smem + POFF + w * 2048;
  const int qt = w;

  f32x4 o[4];
  float m[4], lsum[4];
#pragma unroll
  for (int r = 0; r < 4; ++r) { m[r] = -1e30f; lsum[r] = 0.f; }
#pragma unroll
  for (int nd = 0; nd < 4; ++nd) o[nd] = (f32x4){0.f, 0.f, 0.f, 0.f};

  const int nc = (qt >> 2) + 1;
#pragma unroll 1
  for (int c = 0; c < nc; ++c) {
    // ---- S = Q K^T (pi-consistent on both operands) ----
    f32x4 s[4];
#pragma unroll
    for (int nj = 0; nj < 4; ++nj) s[nj] = (f32x4){0.f, 0.f, 0.f, 0.f};
#pragma unroll
    for (int nj = 0; nj < 4; ++nj) {
      const int rb = c * 64 + nj * 16 + li;
      s16x8 kf0 = *reinterpret_cast<const s16x8*>(
          smem + rb * 128 + (((0 + g) ^ (rb & 7)) << 4));
      s16x8 kf1 = *reinterpret_cast<const s16x8*>(
          smem + rb * 128 + (((4 + g) ^ (rb & 7)) << 4));
      s[nj] = MFMA16(qf0, kf0, s[nj], 0, 0, 0);
      s[nj] = MFMA16(qf1, kf1, s[nj], 0, 0, 0);
    }
    const bool last = (c == nc - 1);
    // ---- scale + causal mask ----
#pragma unroll
    for (int nj = 0; nj < 4; ++nj)
#pragma unroll
      for (int r = 0; r < 4; ++r) {
        float v = s[nj][r] * 0.125f;
        if (last && (c * 64 + nj * 16 + li) > (qt * 16 + g * 4 + r)) v = -1e30f;
        s[nj][r] = v;
      }
    // ---- online max ----
    float alpha[4];
#pragma unroll
    for (int r = 0; r < 4; ++r) {
      float pm = fmaxf(fmaxf(s[0][r], s[1][r]), fmaxf(s[2][r], s[3][r]));
      pm = fmaxf(pm, __shfl_xor(pm, 1));
      pm = fmaxf(pm, __shfl_xor(pm, 2));
      pm = fmaxf(pm, __shfl_xor(pm, 4));
      pm = fmaxf(pm, __shfl_xor(pm, 8));
      float mn = fmaxf(m[r], pm);
      alpha[r] = __expf(m[r] - mn);
      m[r] = mn;
    }
    // ---- P = exp(S-m) -> per-wave LDS (swizzled) ----
    float psum[4] = {0.f, 0.f, 0.f, 0.f};
#pragma unroll
    for (int nj = 0; nj < 4; ++nj)
#pragma unroll
      for (int r = 0; r < 4; ++r) {
        float p = __expf(s[nj][r] - m[r]);
        psum[r] += p;
        int rowp = g * 4 + r;
        *reinterpret_cast<u16*>(
            Pw + rowp * 128 + ((nj * 32 + li * 2) ^ ((rowp & 7) << 4))) = f2bf(p);
      }
#pragma unroll
    for (int r = 0; r < 4; ++r) {
      float ps = psum[r];
      ps += __shfl_xor(ps, 1);
      ps += __shfl_xor(ps, 2);
      ps += __shfl_xor(ps, 4);
      ps += __shfl_xor(ps, 8);
      lsum[r] = lsum[r] * alpha[r] + ps;
    }
#pragma unroll
    for (int nd = 0; nd < 4; ++nd)
#pragma unroll
      for (int r = 0; r < 4; ++r) o[nd][r] *= alpha[r];

    __asm__ volatile("s_waitcnt lgkmcnt(0)" ::: "memory");
    // ---- O += P V ----
    s16x8 pa[2];
#pragma unroll
    for (int kk = 0; kk < 2; ++kk)
      pa[kk] = *reinterpret_cast<const s16x8*>(
          Pw + li * 128 + (((kk * 4 + g) ^ (li & 7)) << 4));
#pragma unroll
    for (int nd = 0; nd < 4; ++nd) {
#pragma unroll
      for (int kk = 0; kk < 2; ++kk) {
        const int d = nd * 16 + li;
        s16x8 vf = *reinterpret_cast<const s16x8*>(
            smem + VTOF + d * 512 + ((c * 128 + kk * 64 + g * 16) ^ ((d & 7) << 4)));
        o[nd] = MFMA16(pa[kk], vf, o[nd], 0, 0, 0);
      }
    }
  }
  // ---- output ----
#pragma unroll
  for (int r = 0; r < 4; ++r) lsum[r] = 1.f / lsum[r];
#pragma unroll
  for (int nd = 0; nd < 4; ++nd)
#pragma unroll
    for (int r = 0; r < 4; ++r)
      out[(bbase + qt * 16 + g * 4 + r) * 64 + nd * 16 + li] = o[nd][r] * lsum[r];
}

extern "C" void kernel_launch(void* const* d_in, const int* in_sizes, int n_in,
                              void* d_out, int out_size, void* d_ws, size_t ws_size,
                              hipStream_t stream) {
  const float* x  = (const float*)d_in[0];
  const float* WQ = (const float*)d_in[1];
  const float* WK = (const float*)d_in[2];
  const float* WV = (const float*)d_in[3];
  float* out = (float*)d_out;

  head_kernel<<<dim3(512), dim3(1024), 0, stream>>>(x, WQ, WK, WV, out);
}